// Round 7
// baseline (326.021 us; speedup 1.0000x reference)
//
#include <hip/hip_runtime.h>

typedef unsigned short u16;

#define N_SP   3136     // 56*56
#define BNCOL  25088    // B * N_SP
#define NDIM   384
#define NINNER 512
#define SCALE_F 0.125f

typedef __attribute__((ext_vector_type(8))) short bf16x8;
typedef __attribute__((ext_vector_type(4))) float f32x4;

#define AS1 __attribute__((address_space(1)))
#define AS3 __attribute__((address_space(3)))

__device__ __forceinline__ float bf2f(u16 u) {
  union { unsigned int i; float f; } v; v.i = ((unsigned int)u) << 16; return v.f;
}
__device__ __forceinline__ u16 f2bf(float f) {
  union { float f; unsigned int i; } v; v.f = f;
  unsigned int r = v.i + 0x7fffu + ((v.i >> 16) & 1u);   // RNE
  return (u16)(r >> 16);
}

// async global->LDS, 16B per lane. lds base must be wave-uniform; lane i lands at lds + i*16B.
__device__ __forceinline__ void g2l16(const u16* g, u16* l) {
  __builtin_amdgcn_global_load_lds((const AS1 unsigned int*)g,
                                   (AS3 unsigned int*)l, 16, 0, 0);
}

// ---------- weight fp32 -> bf16 (Wqkv = [Wq; Wkv], Wo) + BN-folded dw weights ----------
__global__ __launch_bounds__(256) void cvt_kernel(
    const float* __restrict__ a, const float* __restrict__ b, const float* __restrict__ c,
    u16* __restrict__ wqkv, u16* __restrict__ wo_o,
    const float* __restrict__ qdw, const float* __restrict__ qg, const float* __restrict__ qb2,
    const float* __restrict__ qm,  const float* __restrict__ qv,
    const float* __restrict__ kdw, const float* __restrict__ kg, const float* __restrict__ kb2,
    const float* __restrict__ km,  const float* __restrict__ kvv,
    float* __restrict__ fused)
{
  int i = blockIdx.x * 256 + threadIdx.x;
  if (i < 196608) wqkv[i] = f2bf(a[i]);           // Wq rows 0..511
  wqkv[196608 + i] = f2bf(b[i]);                  // Wkv rows 512..1535 (grid = 393216)
  if (i < 196608) wo_o[i] = f2bf(c[i]);
  if (i < NDIM) {
    float invq = qg[i] * rsqrtf(qv[i] + 1e-5f);
    float invk = kg[i] * rsqrtf(kvv[i] + 1e-5f);
    float* f = fused + i * 20;
#pragma unroll
    for (int j = 0; j < 9; ++j) { f[j] = qdw[i*9+j] * invq; f[10+j] = kdw[i*9+j] * invk; }
    f[9]  = qb2[i] - qm[i] * invq;
    f[19] = kb2[i] - km[i] * invk;
  }
}

// ---------- fused depthwise 3x3 conv + BN, output interleaved (BN, 768) bf16 ----------
__global__ __launch_bounds__(256) void dwbn_kernel(
    const float* __restrict__ x, const float* __restrict__ fused,
    u16* __restrict__ yact)
{
  __shared__ u16 Lq[64][40];
  __shared__ u16 Lk[64][40];
  int tid = threadIdx.x;
  int bb = blockIdx.z, c0 = blockIdx.y * 32, p0 = blockIdx.x * 64;
  int pl = tid & 63;
  int cg = __builtin_amdgcn_readfirstlane(tid >> 6);   // wave-uniform channel group
  int p = p0 + pl;
  int h = p / 56, w = p - h * 56;
  int roff[3], coff[3];
  float mr[3], mc[3];
#pragma unroll
  for (int d = 0; d < 3; ++d) {
    int r = h + d - 1;
    bool vr = (r >= 0) && (r < 56);
    roff[d] = (vr ? r : h) * 56;
    mr[d] = vr ? 1.f : 0.f;
    int cc = w + d - 1;
    bool vc = (cc >= 0) && (cc < 56);
    coff[d] = vc ? cc : w;
    mc[d] = vc ? 1.f : 0.f;
  }
  float m9[9];
#pragma unroll
  for (int dh = 0; dh < 3; ++dh)
#pragma unroll
    for (int dw = 0; dw < 3; ++dw) m9[dh*3+dw] = mr[dh] * mc[dw];

  __attribute__((aligned(16))) u16 oq[8], ok[8];
#pragma unroll
  for (int i = 0; i < 8; ++i) {
    int c = c0 + cg * 8 + i;
    const float* xp = x + ((size_t)bb * NDIM + c) * N_SP;
    const float* f = fused + c * 20;
    float v[9];
#pragma unroll
    for (int dh = 0; dh < 3; ++dh)
#pragma unroll
      for (int dw = 0; dw < 3; ++dw)
        v[dh*3+dw] = xp[roff[dh] + coff[dw]];
    float sq = f[9], sk = f[19];
#pragma unroll
    for (int j = 0; j < 9; ++j) {
      float xm = v[j] * m9[j];
      sq += xm * f[j];
      sk += xm * f[10+j];
    }
    oq[i] = f2bf(sq); ok[i] = f2bf(sk);
  }
  *(ushort4*)&Lq[pl][cg * 8]     = *(ushort4*)&oq[0];
  *(ushort4*)&Lq[pl][cg * 8 + 4] = *(ushort4*)&oq[4];
  *(ushort4*)&Lk[pl][cg * 8]     = *(ushort4*)&ok[0];
  *(ushort4*)&Lk[pl][cg * 8 + 4] = *(ushort4*)&ok[4];
  __syncthreads();
  int pr = tid >> 2, cc2 = (tid & 3) * 8;
  size_t g = ((size_t)bb * N_SP + p0 + pr) * 768 + c0 + cc2;
  *(ushort4*)(yact + g)            = *(ushort4*)&Lq[pr][cc2];
  *(ushort4*)(yact + g + 4)        = *(ushort4*)&Lq[pr][cc2 + 4];
  *(ushort4*)(yact + g + 384)      = *(ushort4*)&Lk[pr][cc2];
  *(ushort4*)(yact + g + 388)      = *(ushort4*)&Lk[pr][cc2 + 4];
}

// ---------- unified MFMA GEMM, direct-store epilogues ----------
// mode 0 (QKV): A=Wqkv (1536x384), B=Yact (BN x 768, k-window by m-tile),
//               D[m=c][n=bn] -> bf16 QKVb (1536, BNCOL). Kd=384, bstride=768.
// mode 1 (out): A=Wo (384x512), B=OutA (BN,512), +bias, fp32 NCHW scatter. Kd=512.
// grid = 8 * 25 * Mt; swizzle: xcd=bid&7, mt fastest -> B n-tile L2-resident per XCD.
__global__ __launch_bounds__(256) void mfma_gemm(
    const u16* __restrict__ A, const u16* __restrict__ B,
    u16* __restrict__ D, const float* __restrict__ bias, float* __restrict__ Out,
    int Kd, int bstride, int Mt, int mode)
{
  __shared__ u16 As[128 * 32];
  __shared__ u16 Bs[128 * 32];
  int bid = blockIdx.x;
  int x = bid & 7, ii = bid >> 3;
  int nl = ii / Mt, mt = ii - nl * Mt;
  int nt = nl * 8 + x;
  if (nt >= 196) return;
  int m0 = mt * 128, n0 = nt * 128;
  int koff = (mode == 0 && mt >= 4) ? 384 : 0;

  int tid = threadIdx.x;
  int lane = tid & 63, wv = tid >> 6;
  int wm = (wv >> 1) * 64, wn = (wv & 1) * 64;
  int srow = lane >> 2;          // 0..15
  int sch = (lane & 3) * 8;      // k chunk
  int arow0 = wv * 32;           // each wave stages 32 rows of A and B
  const u16* Ag = A + (size_t)(m0 + arow0 + srow) * Kd + sch;
  const u16* Bg = B + (size_t)(n0 + arow0 + srow) * bstride + koff + sch;
  u16* Al = &As[arow0 * 32];
  u16* Bl = &Bs[arow0 * 32];
  f32x4 acc[4][4];
#pragma unroll
  for (int i = 0; i < 4; ++i)
#pragma unroll
    for (int j = 0; j < 4; ++j) acc[i][j] = (f32x4){0.f, 0.f, 0.f, 0.f};

  int ml = lane & 15, q8 = (lane >> 4) * 8;
  for (int k0 = 0; k0 < Kd; k0 += 32) {
    g2l16(Ag + k0, Al);
    g2l16(Ag + k0 + (size_t)16 * Kd, Al + 16 * 32);
    g2l16(Bg + k0, Bl);
    g2l16(Bg + k0 + (size_t)16 * bstride, Bl + 16 * 32);
    __syncthreads();
    bf16x8 af[4], bfr[4];
#pragma unroll
    for (int i = 0; i < 4; ++i) {
      af[i]  = *(const bf16x8*)&As[(wm + i * 16 + ml) * 32 + q8];
      bfr[i] = *(const bf16x8*)&Bs[(wn + i * 16 + ml) * 32 + q8];
    }
#pragma unroll
    for (int i = 0; i < 4; ++i)
#pragma unroll
      for (int j = 0; j < 4; ++j)
        acc[i][j] = __builtin_amdgcn_mfma_f32_16x16x32_bf16(af[i], bfr[j], acc[i][j], 0, 0, 0);
    __syncthreads();
  }

  int q4 = (lane >> 4) * 4;
  if (mode == 0) {
#pragma unroll
    for (int i = 0; i < 4; ++i)
#pragma unroll
      for (int j = 0; j < 4; ++j) {
        size_t base = (size_t)(m0 + wm + i * 16 + q4) * BNCOL + n0 + wn + j * 16 + ml;
#pragma unroll
        for (int r = 0; r < 4; ++r)
          D[base + (size_t)r * BNCOL] = f2bf(acc[i][j][r]);
      }
  } else {
#pragma unroll
    for (int i = 0; i < 4; ++i)
#pragma unroll
      for (int j = 0; j < 4; ++j) {
        int n = n0 + wn + j * 16 + ml;
        int bb = n / N_SP, p = n - bb * N_SP;
#pragma unroll
        for (int r = 0; r < 4; ++r) {
          int m = m0 + wm + i * 16 + q4 + r;
          Out[((size_t)bb * NDIM + m) * N_SP + p] = acc[i][j][r] + bias[m];
        }
      }
  }
}

// ---------- diag[h][bn] = SCALE * sum_d Q[d][bn] K[d][bn] ; m0 = sum ----------
// Q rows 0..511, K rows 512..1023 of QKVb (c, bn): fully coalesced
__global__ __launch_bounds__(256) void diag_kernel(
    const u16* __restrict__ QKV, float* __restrict__ dg, float* __restrict__ m0)
{
  int hh = blockIdx.y;
  int bn = blockIdx.x * 256 + threadIdx.x;
  const u16* qp = QKV + (size_t)(hh * 64) * BNCOL + bn;
  const u16* kp = QKV + (size_t)(512 + hh * 64) * BNCOL + bn;
  float s = 0.f;
#pragma unroll 8
  for (int d = 0; d < 64; ++d)
    s += bf2f(qp[(size_t)d * BNCOL]) * bf2f(kp[(size_t)d * BNCOL]);
  s *= SCALE_F;
  dg[(size_t)hh * BNCOL + bn] = s;
  float r = s;
#pragma unroll
  for (int off = 32; off > 0; off >>= 1) r += __shfl_down(r, off);
  __shared__ float wsum[4];
  if ((threadIdx.x & 63) == 0) wsum[threadIdx.x >> 6] = r;
  __syncthreads();
  if (threadIdx.x == 0) atomicAdd(m0, wsum[0] + wsum[1] + wsum[2] + wsum[3]);
}

// ---------- ktvT[bh][e][d] = sum_p K[d][p] V[e][p]  (MFMA, frags from global) ----------
// grid (14, 64): wave w owns d-rows [16w,16w+16); no LDS, no barriers. Stored TRANSPOSED.
__global__ __launch_bounds__(256) void ktv_kernel(
    const u16* __restrict__ QKV, float* __restrict__ ktv)
{
  int bh = blockIdx.y, bb = bh >> 3, hh = bh & 7;
  int tid = threadIdx.x;
  int w = tid >> 6, lane = tid & 63;
  int ml = lane & 15, quad = lane >> 4, q8 = quad * 8;
  size_t colbase = (size_t)bb * N_SP + blockIdx.x * 224 + q8;
  const u16* Ar = QKV + (size_t)(512 + hh * 64 + w * 16 + ml) * BNCOL + colbase;
  const u16* Br = QKV + (size_t)(1024 + hh * 64 + ml) * BNCOL + colbase;
  f32x4 acc[4];
#pragma unroll
  for (int j = 0; j < 4; ++j) acc[j] = (f32x4){0.f, 0.f, 0.f, 0.f};
#pragma unroll
  for (int t = 0; t < 7; ++t) {
    int po = t * 32;
    bf16x8 a = *(const bf16x8*)(Ar + po);
#pragma unroll
    for (int j = 0; j < 4; ++j) {
      bf16x8 b = *(const bf16x8*)(Br + (size_t)j * 16 * BNCOL + po);
      acc[j] = __builtin_amdgcn_mfma_f32_16x16x32_bf16(a, b, acc[j], 0, 0, 0);
    }
  }
  float* kt = ktv + bh * 4096;   // [e][d]
#pragma unroll
  for (int j = 0; j < 4; ++j)
#pragma unroll
    for (int r = 0; r < 4; ++r)
      atomicAdd(&kt[(j * 16 + ml) * 64 + w * 16 + quad * 4 + r], acc[j][r]);
}

// ---------- out[p][e] = (m0 - diag[p])*V[e][p] + SCALE * sum_d ktvT[e][d]*Q[d][p] ----------
// MFMA: A = ktvT (LDS, [e][d] bf16), B-frag gathered from Q (c,bn) global.
__global__ __launch_bounds__(256) void attn_out_kernel(
    const u16* __restrict__ QKV, const float* __restrict__ dg,
    const float* __restrict__ ktv, const float* __restrict__ m0p,
    u16* __restrict__ OutA)
{
  __shared__ u16 Kt[64][72];    // ktvT [e][d] bf16
  __shared__ u16 T2[64][72];    // out transpose [p][e]
  __shared__ float ds2[64];
  int bh = blockIdx.y, bb = bh >> 3, hh = bh & 7;
  int p0 = blockIdx.x * 64;
  int tid = threadIdx.x;
  const float* kt = ktv + bh * 4096;           // [e][d]
  for (int l = tid; l < 4096; l += 256) Kt[l >> 6][l & 63] = f2bf(kt[l]);
  size_t pb = (size_t)bb * N_SP + p0;
  if (tid < 64) ds2[tid] = dg[(size_t)hh * BNCOL + pb + tid];
  __syncthreads();
  int w = tid >> 6, lane = tid & 63;
  int ml = lane & 15, quad = lane >> 4, q8 = quad * 8;
  bf16x8 a0 = *(const bf16x8*)&Kt[w * 16 + ml][q8];        // A[e][d] chunk 0
  bf16x8 a1 = *(const bf16x8*)&Kt[w * 16 + ml][32 + q8];   // chunk 1
  const u16* Qbase = QKV + (size_t)(hh * 64 + q8) * BNCOL + pb + ml;
  f32x4 acc[4];
#pragma unroll
  for (int j = 0; j < 4; ++j) acc[j] = (f32x4){0.f, 0.f, 0.f, 0.f};
#pragma unroll
  for (int j = 0; j < 4; ++j) {
    bf16x8 b0, b1;
#pragma unroll
    for (int jj = 0; jj < 8; ++jj) {
      b0[jj] = (short)Qbase[(size_t)jj * BNCOL + j * 16];
      b1[jj] = (short)Qbase[(size_t)(32 + jj) * BNCOL + j * 16];
    }
    acc[j] = __builtin_amdgcn_mfma_f32_16x16x32_bf16(a0, b0, acc[j], 0, 0, 0);
    acc[j] = __builtin_amdgcn_mfma_f32_16x16x32_bf16(a1, b1, acc[j], 0, 0, 0);
  }
  float m0v = *m0p;
#pragma unroll
  for (int j = 0; j < 4; ++j) {
    int pcol = j * 16 + ml;
    float dvm = m0v - ds2[pcol];
    const u16* vr = QKV + (size_t)(1024 + hh * 64 + w * 16 + quad * 4) * BNCOL + pb + pcol;
#pragma unroll
    for (int r = 0; r < 4; ++r) {
      float o = SCALE_F * acc[j][r] + dvm * bf2f(vr[(size_t)r * BNCOL]);
      T2[pcol][w * 16 + quad * 4 + r] = f2bf(o);
    }
  }
  __syncthreads();
  int pl = tid >> 2, ec = (tid & 3) * 16;
  u16* gp = OutA + (pb + pl) * NINNER + hh * 64 + ec;
  *(ushort4*)gp        = *(ushort4*)&T2[pl][ec];
  *(ushort4*)(gp + 4)  = *(ushort4*)&T2[pl][ec + 4];
  *(ushort4*)(gp + 8)  = *(ushort4*)&T2[pl][ec + 8];
  *(ushort4*)(gp + 12) = *(ushort4*)&T2[pl][ec + 12];
}

extern "C" void kernel_launch(void* const* d_in, const int* in_sizes, int n_in,
                              void* d_out, int out_size, void* d_ws, size_t ws_size,
                              hipStream_t stream)
{
  (void)in_sizes; (void)n_in; (void)out_size; (void)ws_size;
  const float* x      = (const float*)d_in[0];
  const float* wq_dw  = (const float*)d_in[1];
  const float* wq_g   = (const float*)d_in[2];
  const float* wq_b   = (const float*)d_in[3];
  const float* wq_m   = (const float*)d_in[4];
  const float* wq_v   = (const float*)d_in[5];
  const float* wq_pw  = (const float*)d_in[6];
  const float* wkv_dw = (const float*)d_in[7];
  const float* wkv_g  = (const float*)d_in[8];
  const float* wkv_b  = (const float*)d_in[9];
  const float* wkv_m  = (const float*)d_in[10];
  const float* wkv_v  = (const float*)d_in[11];
  const float* wkv_pw = (const float*)d_in[12];
  const float* wo     = (const float*)d_in[13];
  const float* bo     = (const float*)d_in[14];
  float* out = (float*)d_out;

  char* ws = (char*)d_ws;
  size_t off = 0;
  auto alloc = [&](size_t bytes) {
    void* p = ws + off; off = (off + bytes + 255) & ~(size_t)255; return p;
  };
  u16* Yact  = (u16*)alloc((size_t)BNCOL * 768 * 2);         // 38.5 MB  (BN, 768)
  u16* QKVb  = (u16*)alloc((size_t)1536 * BNCOL * 2);        // 77.1 MB  (1536, BN): Q 0..511, K 512..1023, V 1024..1535
  float* dgb  = (float*)alloc((size_t)8 * BNCOL * 4);        // 0.80 MB  [h][bn]
  float* ktvb = (float*)alloc((size_t)64 * 4096 * 4 + 64);   // 1.05 MB (+m0 tail)
  u16* Wqkv = (u16*)alloc((size_t)1536 * NDIM * 2);          // 1.18 MB
  u16* Wo   = (u16*)alloc((size_t)NDIM * NINNER * 2);        // 0.39 MB
  float* fused = (float*)alloc((size_t)NDIM * 20 * 4);       // 30.7 KB
  float* m0 = ktvb + 64 * 4096;
  u16* OutA = Yact;   // alias: Yact dead after qkv gemm; 25.7 MB fits in its 38.5 MB

  hipMemsetAsync(ktvb, 0, (size_t)64 * 4096 * 4 + 4, stream);

  cvt_kernel<<<1536, 256, 0, stream>>>(wq_pw, wkv_pw, wo, Wqkv, Wo,
                                       wq_dw, wq_g, wq_b, wq_m, wq_v,
                                       wkv_dw, wkv_g, wkv_b, wkv_m, wkv_v, fused);

  dwbn_kernel<<<dim3(49, 12, 8), 256, 0, stream>>>(x, fused, Yact);

  // fused QKV projection: 12 m-tiles x 196 n-tiles, all direct-store (c, bn)
  mfma_gemm<<<dim3(8 * 25 * 12), 256, 0, stream>>>(Wqkv, Yact, QKVb, nullptr, nullptr,
                                                   NDIM, 768, 12, 0);

  diag_kernel<<<dim3(98, 8), 256, 0, stream>>>(QKVb, dgb, m0);
  ktv_kernel<<<dim3(14, 64), 256, 0, stream>>>(QKVb, ktvb);
  attn_out_kernel<<<dim3(49, 64), 256, 0, stream>>>(QKVb, dgb, ktvb, m0, OutA);

  mfma_gemm<<<dim3(8 * 25 * 3), 256, 0, stream>>>(Wo, OutA, nullptr, bo, out,
                                                  NINNER, NINNER, 3, 1);
}

// Round 8
// 287.894 us; speedup vs baseline: 1.1324x; 1.1324x over previous
//
#include <hip/hip_runtime.h>

typedef unsigned short u16;

#define N_SP   3136     // 56*56
#define BNCOL  25088    // B * N_SP
#define NDIM   384
#define NINNER 512
#define SCALE_F 0.125f

typedef __attribute__((ext_vector_type(8))) short bf16x8;
typedef __attribute__((ext_vector_type(4))) float f32x4;

#define AS1 __attribute__((address_space(1)))
#define AS3 __attribute__((address_space(3)))

__device__ __forceinline__ float bf2f(u16 u) {
  union { unsigned int i; float f; } v; v.i = ((unsigned int)u) << 16; return v.f;
}
__device__ __forceinline__ u16 f2bf(float f) {
  union { float f; unsigned int i; } v; v.f = f;
  unsigned int r = v.i + 0x7fffu + ((v.i >> 16) & 1u);   // RNE
  return (u16)(r >> 16);
}

// async global->LDS, 16B per lane. lds base must be wave-uniform; lane i lands at lds + i*16B.
__device__ __forceinline__ void g2l16(const u16* g, u16* l) {
  __builtin_amdgcn_global_load_lds((const AS1 unsigned int*)g,
                                   (AS3 unsigned int*)l, 16, 0, 0);
}

// ---------- weight fp32 -> bf16 convert + BN-folded depthwise weights ----------
__global__ __launch_bounds__(256) void cvt_kernel(
    const float* __restrict__ a, const float* __restrict__ b, const float* __restrict__ c,
    u16* __restrict__ oa, u16* __restrict__ ob, u16* __restrict__ oc,
    const float* __restrict__ qdw, const float* __restrict__ qg, const float* __restrict__ qb2,
    const float* __restrict__ qm,  const float* __restrict__ qv,
    const float* __restrict__ kdw, const float* __restrict__ kg, const float* __restrict__ kb2,
    const float* __restrict__ km,  const float* __restrict__ kvv,
    float* __restrict__ fused)
{
  int i = blockIdx.x * 256 + threadIdx.x;
  if (i < 196608) oa[i] = f2bf(a[i]);
  ob[i] = f2bf(b[i]);               // grid sized exactly to 393216
  if (i < 196608) oc[i] = f2bf(c[i]);
  if (i < NDIM) {
    float invq = qg[i] * rsqrtf(qv[i] + 1e-5f);
    float invk = kg[i] * rsqrtf(kvv[i] + 1e-5f);
    float* f = fused + i * 20;
#pragma unroll
    for (int j = 0; j < 9; ++j) { f[j] = qdw[i*9+j] * invq; f[10+j] = kdw[i*9+j] * invk; }
    f[9]  = qb2[i] - qm[i] * invq;
    f[19] = kb2[i] - km[i] * invk;
  }
}

// ---------- fused depthwise 3x3 conv + BN (q and kv paths), output (BN, C) bf16 ----------
__global__ __launch_bounds__(256) void dwbn_kernel(
    const float* __restrict__ x, const float* __restrict__ fused,
    u16* __restrict__ yq, u16* __restrict__ ykv)
{
  __shared__ u16 Lq[64][40];
  __shared__ u16 Lk[64][40];
  int tid = threadIdx.x;
  int bb = blockIdx.z, c0 = blockIdx.y * 32, p0 = blockIdx.x * 64;
  int pl = tid & 63;
  int cg = __builtin_amdgcn_readfirstlane(tid >> 6);   // wave-uniform channel group
  int p = p0 + pl;
  int h = p / 56, w = p - h * 56;
  int roff[3], coff[3];
  float mr[3], mc[3];
#pragma unroll
  for (int d = 0; d < 3; ++d) {
    int r = h + d - 1;
    bool vr = (r >= 0) && (r < 56);
    roff[d] = (vr ? r : h) * 56;
    mr[d] = vr ? 1.f : 0.f;
    int cc = w + d - 1;
    bool vc = (cc >= 0) && (cc < 56);
    coff[d] = vc ? cc : w;
    mc[d] = vc ? 1.f : 0.f;
  }
  float m9[9];
#pragma unroll
  for (int dh = 0; dh < 3; ++dh)
#pragma unroll
    for (int dw = 0; dw < 3; ++dw) m9[dh*3+dw] = mr[dh] * mc[dw];

  __attribute__((aligned(16))) u16 oq[8], ok[8];
#pragma unroll
  for (int i = 0; i < 8; ++i) {
    int c = c0 + cg * 8 + i;
    const float* xp = x + ((size_t)bb * NDIM + c) * N_SP;
    const float* f = fused + c * 20;
    float v[9];
#pragma unroll
    for (int dh = 0; dh < 3; ++dh)
#pragma unroll
      for (int dw = 0; dw < 3; ++dw)
        v[dh*3+dw] = xp[roff[dh] + coff[dw]];
    float sq = f[9], sk = f[19];
#pragma unroll
    for (int j = 0; j < 9; ++j) {
      float xm = v[j] * m9[j];
      sq += xm * f[j];
      sk += xm * f[10+j];
    }
    oq[i] = f2bf(sq); ok[i] = f2bf(sk);
  }
  *(ushort4*)&Lq[pl][cg * 8]     = *(ushort4*)&oq[0];
  *(ushort4*)&Lq[pl][cg * 8 + 4] = *(ushort4*)&oq[4];
  *(ushort4*)&Lk[pl][cg * 8]     = *(ushort4*)&ok[0];
  *(ushort4*)&Lk[pl][cg * 8 + 4] = *(ushort4*)&ok[4];
  __syncthreads();
  int pr = tid >> 2, cc2 = (tid & 3) * 8;
  size_t g = ((size_t)bb * N_SP + p0 + pr) * NDIM + c0 + cc2;
  *(ushort4*)(yq + g)      = *(ushort4*)&Lq[pr][cc2];
  *(ushort4*)(yq + g + 4)  = *(ushort4*)&Lq[pr][cc2 + 4];
  *(ushort4*)(ykv + g)     = *(ushort4*)&Lk[pr][cc2];
  *(ushort4*)(ykv + g + 4) = *(ushort4*)&Lk[pr][cc2 + 4];
}

// ---------- MFMA GEMM: D[m][n] = sum_k A[m][k] * B[n][k]  (NT form) ----------
// mode 0: LDS-transpose, store bf16 rows of n: Cout[n][m] (stride Cstride).
// mode 1: +bias, fp32 NCHW scatter (m = channel, n = bn).
// Swizzle: Nt==8 (KV, shared tile is A): bid&7 == mt&7 -> all 8 nt-siblings of an
//          A-tile on ONE XCD (L2-resident). Else (shared tile is B): old scheme,
//          mt-siblings of one nt already share bid&7.
__global__ __launch_bounds__(256) void mfma_gemm(
    const u16* __restrict__ A, const u16* __restrict__ B, int Kd,
    u16* __restrict__ Cout, int Cstride,
    int mode, const float* __restrict__ bias, float* __restrict__ Out, int Mt, int Nt)
{
  __shared__ union {
    struct { u16 A[128 * 32]; u16 B[128 * 32]; } s;   // [row][k] 8KB each
    u16 T[64 * 132];                                   // epilogue transpose chunk (16.9KB)
  } lds;
  int bid = blockIdx.x, mt, nt;
  if (Nt == 8) {
    int low = bid & 7;                 // XCD slot == mt & 7
    nt = (bid >> 3) & 7;
    mt = (bid >> 6) * 8 + low;
    if (mt >= Mt) return;
  } else {
    int r = bid & 7, g = bid >> 3;
    mt = g % Mt; nt = (g / Mt) * 8 + r;
    if (nt >= Nt) return;
  }
  int m0 = mt * 128, n0 = nt * 128;

  int tid = threadIdx.x;
  int lane = tid & 63, wv = tid >> 6;
  int wm = (wv >> 1) * 64, wn = (wv & 1) * 64;
  int srow = lane >> 2;          // 0..15
  int sch = (lane & 3) * 8;      // k chunk
  int arow0 = wv * 32;           // each wave stages 32 rows of A and B
  const u16* Ag = A + (size_t)(m0 + arow0 + srow) * Kd + sch;
  const u16* Bg = B + (size_t)(n0 + arow0 + srow) * Kd + sch;
  u16* Al = &lds.s.A[arow0 * 32];
  u16* Bl = &lds.s.B[arow0 * 32];
  f32x4 acc[4][4];
#pragma unroll
  for (int i = 0; i < 4; ++i)
#pragma unroll
    for (int j = 0; j < 4; ++j) acc[i][j] = (f32x4){0.f, 0.f, 0.f, 0.f};

  int ml = lane & 15, q8 = (lane >> 4) * 8;
  for (int k0 = 0; k0 < Kd; k0 += 32) {
    g2l16(Ag + k0, Al);
    g2l16(Ag + k0 + (size_t)16 * Kd, Al + 16 * 32);
    g2l16(Bg + k0, Bl);
    g2l16(Bg + k0 + (size_t)16 * Kd, Bl + 16 * 32);
    __syncthreads();
    bf16x8 af[4], bfr[4];
#pragma unroll
    for (int i = 0; i < 4; ++i) {
      af[i]  = *(const bf16x8*)&lds.s.A[(wm + i * 16 + ml) * 32 + q8];
      bfr[i] = *(const bf16x8*)&lds.s.B[(wn + i * 16 + ml) * 32 + q8];
    }
#pragma unroll
    for (int i = 0; i < 4; ++i)
#pragma unroll
      for (int j = 0; j < 4; ++j)
        acc[i][j] = __builtin_amdgcn_mfma_f32_16x16x32_bf16(af[i], bfr[j], acc[i][j], 0, 0, 0);
    __syncthreads();
  }

  if (mode == 0) {
    int q4 = (lane >> 4) * 4;
#pragma unroll
    for (int ph = 0; ph < 2; ++ph) {
      if (ph) __syncthreads();         // previous chunk's readers done
      if ((wv & 1) == ph) {            // waves whose wn == ph*64
#pragma unroll
        for (int i = 0; i < 4; ++i)
#pragma unroll
          for (int j = 0; j < 4; ++j) {
            int nl = j * 16 + ml;      // 0..63 local n
            int m = wm + i * 16 + q4;
            ushort4 o;
            o.x = f2bf(acc[i][j][0]); o.y = f2bf(acc[i][j][1]);
            o.z = f2bf(acc[i][j][2]); o.w = f2bf(acc[i][j][3]);
            *(ushort4*)&lds.T[nl * 132 + m] = o;
          }
      }
      __syncthreads();
#pragma unroll
      for (int it = 0; it < 4; ++it) {
        int nl = it * 16 + (tid >> 4);
        int mc = (tid & 15) * 8;
        ushort4 a = *(ushort4*)&lds.T[nl * 132 + mc];
        ushort4 b = *(ushort4*)&lds.T[nl * 132 + mc + 4];
        u16* gp = Cout + (size_t)(n0 + ph * 64 + nl) * Cstride + m0 + mc;
        *(ushort4*)gp = a;
        *(ushort4*)(gp + 4) = b;
      }
    }
  } else {
    int q4 = (lane >> 4) * 4;
#pragma unroll
    for (int i = 0; i < 4; ++i)
#pragma unroll
      for (int j = 0; j < 4; ++j) {
        int n = n0 + wn + j * 16 + ml;
        int bb = n / N_SP, p = n - bb * N_SP;
#pragma unroll
        for (int rr = 0; rr < 4; ++rr) {
          int m = m0 + wm + i * 16 + q4 + rr;
          Out[((size_t)bb * NDIM + m) * N_SP + p] = acc[i][j][rr] + bias[m];
        }
      }
  }
}

// ---------- diag[bn][h] = SCALE * sum_d Q[bn][d] K[d][bn] ; m0 = sum ----------
// Q (bn,c), K (c,bn): K reads coalesced across lanes, Q rows per-lane (L2-friendly)
__global__ __launch_bounds__(256) void diag_kernel(
    const u16* __restrict__ Q, const u16* __restrict__ KV,
    float* __restrict__ dg, float* __restrict__ m0)
{
  int hh = blockIdx.y;
  int bn = blockIdx.x * 256 + threadIdx.x;
  const u16* qrow = Q + (size_t)bn * NINNER + hh * 64;
  const u16* kcol = KV + (size_t)(hh * 64) * BNCOL + bn;
  float s = 0.f;
#pragma unroll
  for (int d0 = 0; d0 < 64; d0 += 8) {
    ushort4 a = *(const ushort4*)(qrow + d0);
    ushort4 b = *(const ushort4*)(qrow + d0 + 4);
    const u16* kp = kcol + (size_t)d0 * BNCOL;
    s += bf2f(a.x) * bf2f(kp[0]);
    s += bf2f(a.y) * bf2f(kp[(size_t)1 * BNCOL]);
    s += bf2f(a.z) * bf2f(kp[(size_t)2 * BNCOL]);
    s += bf2f(a.w) * bf2f(kp[(size_t)3 * BNCOL]);
    s += bf2f(b.x) * bf2f(kp[(size_t)4 * BNCOL]);
    s += bf2f(b.y) * bf2f(kp[(size_t)5 * BNCOL]);
    s += bf2f(b.z) * bf2f(kp[(size_t)6 * BNCOL]);
    s += bf2f(b.w) * bf2f(kp[(size_t)7 * BNCOL]);
  }
  s *= SCALE_F;
  dg[(size_t)bn * 8 + hh] = s;
  float r = s;
#pragma unroll
  for (int off = 32; off > 0; off >>= 1) r += __shfl_down(r, off);
  __shared__ float wsum[4];
  if ((threadIdx.x & 63) == 0) wsum[threadIdx.x >> 6] = r;
  __syncthreads();
  if (threadIdx.x == 0) atomicAdd(m0, wsum[0] + wsum[1] + wsum[2] + wsum[3]);
}

// ---------- ktv[bh][d][e] = sum_p K[d][p] V[e][p]  (MFMA, frags direct from global) ----------
// grid (14, 64): wave w owns d-rows [16w,16w+16); no LDS, no barriers.
__global__ __launch_bounds__(256) void ktv_kernel(
    const u16* __restrict__ KV, float* __restrict__ ktv)
{
  int bh = blockIdx.y, bb = bh >> 3, hh = bh & 7;
  int tid = threadIdx.x;
  int w = tid >> 6, lane = tid & 63;
  int ml = lane & 15, quad = lane >> 4, q8 = quad * 8;
  size_t colbase = (size_t)bb * N_SP + blockIdx.x * 224 + q8;
  const u16* Ar = KV + (size_t)(hh * 64 + w * 16 + ml) * BNCOL + colbase;
  const u16* Br = KV + (size_t)(NINNER + hh * 64 + ml) * BNCOL + colbase;
  f32x4 acc[4];
#pragma unroll
  for (int j = 0; j < 4; ++j) acc[j] = (f32x4){0.f, 0.f, 0.f, 0.f};
#pragma unroll
  for (int t = 0; t < 7; ++t) {
    int po = t * 32;
    bf16x8 a = *(const bf16x8*)(Ar + po);
#pragma unroll
    for (int j = 0; j < 4; ++j) {
      bf16x8 b = *(const bf16x8*)(Br + (size_t)j * 16 * BNCOL + po);
      acc[j] = __builtin_amdgcn_mfma_f32_16x16x32_bf16(a, b, acc[j], 0, 0, 0);
    }
  }
  float* kt = ktv + bh * 4096;
#pragma unroll
  for (int j = 0; j < 4; ++j)
#pragma unroll
    for (int r = 0; r < 4; ++r)
      atomicAdd(&kt[(w * 16 + quad * 4 + r) * 64 + j * 16 + ml], acc[j][r]);
}

// ---------- out[p][e] = (m0 - diag[p])*V[e][p] + SCALE * sum_d Q[p][d]*ktv[d][e] ----------
// MFMA: A = Q rows (global), B = ktv^T bf16 (LDS). Output (bn, c) via LDS transpose.
__global__ __launch_bounds__(256) void attn_out_kernel(
    const u16* __restrict__ Q, const u16* __restrict__ KV,
    const float* __restrict__ dg, const float* __restrict__ ktv,
    const float* __restrict__ m0p, u16* __restrict__ OutA)
{
  __shared__ u16 Bt[64][72];    // ktv^T [e][d] bf16
  __shared__ u16 T2[64][72];    // out transpose [p][e]
  __shared__ float ds2[64];
  int bh = blockIdx.y, bb = bh >> 3, hh = bh & 7;
  int p0 = blockIdx.x * 64;
  int tid = threadIdx.x;
  const float* kt = ktv + bh * 4096;
  for (int l = tid; l < 4096; l += 256) {
    int d = l >> 6, e = l & 63;
    Bt[e][d] = f2bf(kt[l]);
  }
  if (tid < 64) ds2[tid] = dg[(size_t)(bb * N_SP + p0 + tid) * 8 + hh];
  __syncthreads();
  int w = tid >> 6, lane = tid & 63;
  int ml = lane & 15, quad = lane >> 4, q8 = quad * 8;
  const u16* Ar = Q + ((size_t)bb * N_SP + p0 + w * 16 + ml) * NINNER + hh * 64 + q8;
  bf16x8 a0 = *(const bf16x8*)Ar;
  bf16x8 a1 = *(const bf16x8*)(Ar + 32);
  f32x4 acc[4];
#pragma unroll
  for (int j = 0; j < 4; ++j) acc[j] = (f32x4){0.f, 0.f, 0.f, 0.f};
#pragma unroll
  for (int j = 0; j < 4; ++j) {
    bf16x8 b0 = *(const bf16x8*)&Bt[j * 16 + ml][q8];
    bf16x8 b1 = *(const bf16x8*)&Bt[j * 16 + ml][32 + q8];
    acc[j] = __builtin_amdgcn_mfma_f32_16x16x32_bf16(a0, b0, acc[j], 0, 0, 0);
    acc[j] = __builtin_amdgcn_mfma_f32_16x16x32_bf16(a1, b1, acc[j], 0, 0, 0);
  }
  float m0v = *m0p;
  size_t pcol = (size_t)bb * N_SP + p0 + w * 16 + quad * 4;
#pragma unroll
  for (int j = 0; j < 4; ++j) {
    const u16* vr = KV + (size_t)(NINNER + hh * 64 + j * 16 + ml) * BNCOL + pcol;
    ushort4 vv = *(const ushort4*)vr;
    const u16* vp = (const u16*)&vv;
#pragma unroll
    for (int r = 0; r < 4; ++r) {
      float dvm = m0v - ds2[w * 16 + quad * 4 + r];
      float o = SCALE_F * acc[j][r] + dvm * bf2f(vp[r]);
      T2[w * 16 + quad * 4 + r][j * 16 + ml] = f2bf(o);
    }
  }
  __syncthreads();
  int pl = tid >> 2, ec = (tid & 3) * 16;
  u16* gp = OutA + ((size_t)bb * N_SP + p0 + pl) * NINNER + hh * 64 + ec;
  *(ushort4*)gp        = *(ushort4*)&T2[pl][ec];
  *(ushort4*)(gp + 4)  = *(ushort4*)&T2[pl][ec + 4];
  *(ushort4*)(gp + 8)  = *(ushort4*)&T2[pl][ec + 8];
  *(ushort4*)(gp + 12) = *(ushort4*)&T2[pl][ec + 12];
}

extern "C" void kernel_launch(void* const* d_in, const int* in_sizes, int n_in,
                              void* d_out, int out_size, void* d_ws, size_t ws_size,
                              hipStream_t stream)
{
  (void)in_sizes; (void)n_in; (void)out_size; (void)ws_size;
  const float* x      = (const float*)d_in[0];
  const float* wq_dw  = (const float*)d_in[1];
  const float* wq_g   = (const float*)d_in[2];
  const float* wq_b   = (const float*)d_in[3];
  const float* wq_m   = (const float*)d_in[4];
  const float* wq_v   = (const float*)d_in[5];
  const float* wq_pw  = (const float*)d_in[6];
  const float* wkv_dw = (const float*)d_in[7];
  const float* wkv_g  = (const float*)d_in[8];
  const float* wkv_b  = (const float*)d_in[9];
  const float* wkv_m  = (const float*)d_in[10];
  const float* wkv_v  = (const float*)d_in[11];
  const float* wkv_pw = (const float*)d_in[12];
  const float* wo     = (const float*)d_in[13];
  const float* bo     = (const float*)d_in[14];
  float* out = (float*)d_out;

  char* ws = (char*)d_ws;
  size_t off = 0;
  auto alloc = [&](size_t bytes) {
    void* p = ws + off; off = (off + bytes + 255) & ~(size_t)255; return p;
  };
  u16* yq   = (u16*)alloc((size_t)BNCOL * NDIM * 2);        // 19.27 MB  (BN, 384)
  u16* ykv  = (u16*)alloc((size_t)BNCOL * NDIM * 2);        // 19.27 MB  (BN, 384)
  u16* Qb   = (u16*)alloc((size_t)BNCOL * NINNER * 2);      // 25.69 MB  (BN, 512)
  u16* KVb  = (u16*)alloc((size_t)2 * NINNER * BNCOL * 2);  // 51.38 MB  (1024, BN): K rows 0..511, V rows 512..1023
  float* dgb  = (float*)alloc((size_t)BNCOL * 8 * 4);       // 0.80 MB   (bn, h)
  float* ktvb = (float*)alloc((size_t)64 * 4096 * 4 + 64);  // 1.05 MB (+m0 tail)
  u16* Wq  = (u16*)alloc((size_t)NINNER * NDIM * 2);        // 0.39 MB
  u16* Wkv = (u16*)alloc((size_t)2 * NINNER * NDIM * 2);    // 0.79 MB
  u16* Wo  = (u16*)alloc((size_t)NDIM * NINNER * 2);        // 0.39 MB
  float* fused = (float*)alloc((size_t)NDIM * 20 * 4);      // 30.7 KB BN-folded dw weights
  float* m0 = ktvb + 64 * 4096;
  u16* OutA = yq;   // alias: yq/ykv dead after the pw GEMMs; 25.7 MB fits in their 38.5 MB

  hipMemsetAsync(ktvb, 0, (size_t)64 * 4096 * 4 + 4, stream);

  cvt_kernel<<<1536, 256, 0, stream>>>(wq_pw, wkv_pw, wo, Wq, Wkv, Wo,
                                       wq_dw, wq_g, wq_b, wq_m, wq_v,
                                       wkv_dw, wkv_g, wkv_b, wkv_m, wkv_v, fused);

  dwbn_kernel<<<dim3(49, 12, 8), 256, 0, stream>>>(x, fused, yq, ykv);

  // Q: A=Wq (4 m-tiles), B=yq (196 n-tiles) -> Qb (bn, 512)
  mfma_gemm<<<dim3(4 * 200), 256, 0, stream>>>(Wq, yq, NDIM, Qb, NINNER, 0, nullptr, nullptr, 4, 196);
  // KV swapped: A=ykv (196 m-tiles), B=Wkv (8 n-tiles) -> KVb (1024, bn)
  // grid 25*64: bid&7==mt&7 keeps each ykv tile's 8 nt-siblings on one XCD
  mfma_gemm<<<dim3(25 * 64), 256, 0, stream>>>(ykv, Wkv, NDIM, KVb, BNCOL, 0, nullptr, nullptr, 196, 8);

  diag_kernel<<<dim3(98, 8), 256, 0, stream>>>(Qb, KVb, dgb, m0);
  ktv_kernel<<<dim3(14, 64), 256, 0, stream>>>(KVb, ktvb);
  attn_out_kernel<<<dim3(49, 64), 256, 0, stream>>>(Qb, KVb, dgb, ktvb, m0, OutA);

  mfma_gemm<<<dim3(3 * 200), 256, 0, stream>>>(Wo, OutA, NINNER, nullptr, 0, 1, bo, out, 3, 196);
}